// Round 3
// baseline (422.440 us; speedup 1.0000x reference)
//
#include <hip/hip_runtime.h>
#include <hip/hip_bf16.h>

// Problem constants
#define D_DIM   25088
#define B_ROWS  2048
#define C_CLS   100
#define NT      7            // 7 tiles of 16 cols -> 112 padded classes
#define NPAD    112
#define KSTEPS_TOTAL 784     // 25088 / 32
#define SPLITS  112
#define KSTEPS_PER (KSTEPS_TOTAL / SPLITS)  // 7
#define PREP_G  4            // gsteps per prep block
#define EPS     1e-8f

typedef __bf16 bf16x8 __attribute__((ext_vector_type(8)));
typedef float  f32x4  __attribute__((ext_vector_type(4)));

// RNE float->bf16, pack two into one dword
__device__ __forceinline__ unsigned bfpack2(float lo, float hi) {
    unsigned a = __builtin_bit_cast(unsigned, lo);
    unsigned b = __builtin_bit_cast(unsigned, hi);
    a += 0x7FFFu + ((a >> 16) & 1u);
    b += 0x7FFFu + ((b >> 16) & 1u);
    return (a >> 16) | (b & 0xFFFF0000u);
}

// ---------------- prep: pack weight into MFMA B-fragment order + partial sumsq ----
// Thread t*64+quad*16+n produces the uint4 fragment for class c=t*16+n,
// k = gstep*32 + quad*8 .. +8. wpack[gstep*448 + tid] -> fully coalesced stores.
// Per-wave (fixed t) shfl-reduction over quads gives row-partial sumsq;
// 196 atomicAdds per class accumulate wnorm2[c].
__global__ __launch_bounds__(448) void prep_kernel(const float* __restrict__ w,
                                                   float* __restrict__ wnorm2,
                                                   uint4* __restrict__ wpack) {
    int tid  = threadIdx.x;
    int t    = tid >> 6;
    int quad = (tid >> 4) & 3;
    int n    = tid & 15;
    int c    = t * 16 + n;
    bool real = (c < C_CLS);
    const float* row = w + (size_t)c * D_DIM + quad * 8;
    float s = 0.f;
#pragma unroll
    for (int g = 0; g < PREP_G; ++g) {
        int gstep = blockIdx.x * PREP_G + g;
        f32x4 v0 = {0.f,0.f,0.f,0.f}, v1 = {0.f,0.f,0.f,0.f};
        if (real) {
            v0 = *(const f32x4*)(row + gstep * 32);
            v1 = *(const f32x4*)(row + gstep * 32 + 4);
        }
        s += v0[0]*v0[0] + v0[1]*v0[1] + v0[2]*v0[2] + v0[3]*v0[3]
           + v1[0]*v1[0] + v1[1]*v1[1] + v1[2]*v1[2] + v1[3]*v1[3];
        uint4 o;
        o.x = bfpack2(v0[0], v0[1]);
        o.y = bfpack2(v0[2], v0[3]);
        o.z = bfpack2(v1[0], v1[1]);
        o.w = bfpack2(v1[2], v1[3]);
        wpack[(size_t)gstep * 448 + tid] = o;
    }
    // reduce over the 4 quads holding the same class row
    s += __shfl_xor(s, 16, 64);
    s += __shfl_xor(s, 32, 64);
    if (quad == 0 && real) atomicAdd(&wnorm2[c], s);
}

// ---------------- main GEMM: dot(f_b, w_c) + sumsq(f_b), split-K atomics ----------------
__global__ __launch_bounds__(256) void gemm_kernel(const float* __restrict__ feat,
                                                   const uint4* __restrict__ wpack,
                                                   float* __restrict__ pred,
                                                   float* __restrict__ fnorm2) {
    int tid  = threadIdx.x;
    int wave = tid >> 6, lane = tid & 63;
    int m = lane & 15, quad = lane >> 4;
    int rowbase = blockIdx.x * 64 + wave * 16;
    int row = rowbase + m;
    int gstep0 = blockIdx.y * KSTEPS_PER;

    const float* pA = feat + (size_t)row * D_DIM + gstep0 * 32 + quad * 8;
    const uint4* pB = wpack + (size_t)gstep0 * NT * 64 + lane;

    f32x4 acc[NT];
#pragma unroll
    for (int t = 0; t < NT; ++t) acc[t] = (f32x4){0.f,0.f,0.f,0.f};
    float sumsq = 0.f;

    // depth-2 software pipeline on A
    f32x4 c0 = *(const f32x4*)(pA);
    f32x4 c1 = *(const f32x4*)(pA + 4);
    f32x4 n0 = *(const f32x4*)(pA + 32);
    f32x4 n1 = *(const f32x4*)(pA + 36);

#pragma unroll
    for (int s = 0; s < KSTEPS_PER; ++s) {
        f32x4 f0 = c0, f1 = c1;
        if (s + 2 < KSTEPS_PER) {
            f0 = *(const f32x4*)(pA + (s + 2) * 32);
            f1 = *(const f32x4*)(pA + (s + 2) * 32 + 4);
        }
        sumsq += c0[0]*c0[0] + c0[1]*c0[1] + c0[2]*c0[2] + c0[3]*c0[3]
               + c1[0]*c1[0] + c1[1]*c1[1] + c1[2]*c1[2] + c1[3]*c1[3];
        uint4 ap;
        ap.x = bfpack2(c0[0], c0[1]);
        ap.y = bfpack2(c0[2], c0[3]);
        ap.z = bfpack2(c1[0], c1[1]);
        ap.w = bfpack2(c1[2], c1[3]);
        bf16x8 afrag = __builtin_bit_cast(bf16x8, ap);
#pragma unroll
        for (int t = 0; t < NT; ++t) {
            bf16x8 bfrag = __builtin_bit_cast(bf16x8, pB[s * NT * 64 + t * 64]);
            acc[t] = __builtin_amdgcn_mfma_f32_16x16x32_bf16(afrag, bfrag, acc[t], 0, 0, 0);
        }
        c0 = n0; c1 = n1; n0 = f0; n1 = f1;
    }

    // sumsq: reduce across the 4 quads that share row m
    sumsq += __shfl_xor(sumsq, 16, 64);
    sumsq += __shfl_xor(sumsq, 32, 64);
    if (quad == 0) atomicAdd(&fnorm2[row], sumsq);

    // C/D layout (16x16x32 bf16): col = lane&15, row = quad*4 + reg
#pragma unroll
    for (int t = 0; t < NT; ++t) {
#pragma unroll
        for (int r = 0; r < 4; ++r) {
            int orow = rowbase + quad * 4 + r;
            int ocol = t * 16 + m;
            atomicAdd(&pred[(size_t)orow * NPAD + ocol], acc[t][r]);
        }
    }
}

// ---------------- per-row log-softmax / NLL / argmax: one wave per row ----------------
__global__ __launch_bounds__(256) void finalize_kernel(const float* __restrict__ pred,
                                                       const float* __restrict__ fnorm2,
                                                       const float* __restrict__ wnorm2,
                                                       const int* __restrict__ label,
                                                       float* __restrict__ scal) {
    int row = (blockIdx.x * 256 + threadIdx.x) >> 6;
    int lane = threadIdx.x & 63;
    if (row >= B_ROWS) return;
    float finv = 10.0f / fmaxf(sqrtf(fnorm2[row]), EPS);
    const float* pr = pred + (size_t)row * NPAD;

    int c0 = lane, c1 = lane + 64;
    float l0 = -1e30f, l1 = -1e30f;
    if (c0 < C_CLS) l0 = pr[c0] * (finv / fmaxf(sqrtf(wnorm2[c0]), EPS));
    if (c1 < C_CLS) l1 = pr[c1] * (finv / fmaxf(sqrtf(wnorm2[c1]), EPS));

    // argmax (first-max tie rule: keep smaller index on ties)
    float mx = l0; int am = c0;
    if (l1 > mx) { mx = l1; am = c1; }
    for (int o = 1; o < 64; o <<= 1) {
        float om = __shfl_xor(mx, o, 64);
        int   oa = __shfl_xor(am, o, 64);
        if (om > mx || (om == mx && oa < am)) { mx = om; am = oa; }
    }
    float se = expf(l0 - mx) + expf(l1 - mx);
    for (int o = 1; o < 64; o <<= 1) se += __shfl_xor(se, o, 64);

    int lab = label[row];
    int labc = (lab < 0) ? 0 : lab;
    float lv = (labc >= 64) ? l1 : l0;
    float ll = __shfl(lv, labc & 63, 64);

    if (lane == 0 && lab >= 0) {
        float lse = mx + logf(se);
        atomicAdd(&scal[0], lse - ll);
        atomicAdd(&scal[1], (am == lab) ? 1.f : 0.f);
        atomicAdd(&scal[2], 1.f);
    }
}

__global__ void out_kernel(const float* __restrict__ scal, float* __restrict__ out) {
    out[0] = scal[0] / fmaxf(scal[2], 1.0f);
    out[1] = scal[1] / (scal[2] + 1e-10f);
}

// Workspace layout (bytes):
//   [0, 917504)          pred partials   2048*112 f32   (zeroed)
//   [917504, 925696)     fnorm2          2048 f32       (zeroed)
//   [925696, 925712)     scalars         4 f32          (zeroed, 3 used)
//   [925712, 926160)     wnorm2          112 f32        (zeroed)
//   [926720, 6546432)    wpack bf16 B-fragments (784*448 uint4)
extern "C" void kernel_launch(void* const* d_in, const int* in_sizes, int n_in,
                              void* d_out, int out_size, void* d_ws, size_t ws_size,
                              hipStream_t stream) {
    const float* feat   = (const float*)d_in[0];
    const int*   label  = (const int*)d_in[1];
    const float* weight = (const float*)d_in[2];
    float* out = (float*)d_out;

    char* ws = (char*)d_ws;
    float* pred   = (float*)(ws);
    float* fnorm2 = (float*)(ws + 917504);
    float* scal   = (float*)(ws + 925696);
    float* wnorm2 = (float*)(ws + 925712);
    uint4* wpack  = (uint4*)(ws + 926720);

    hipMemsetAsync(ws, 0, 926160, stream);
    prep_kernel<<<KSTEPS_TOTAL / PREP_G, 448, 0, stream>>>(weight, wnorm2, wpack);
    gemm_kernel<<<dim3(B_ROWS / 64, SPLITS), 256, 0, stream>>>(feat, wpack, pred, fnorm2);
    finalize_kernel<<<B_ROWS / 4, 256, 0, stream>>>(pred, fnorm2, wnorm2, label, scal);
    out_kernel<<<1, 1, 0, stream>>>(scal, out);
}

// Round 4
// 413.268 us; speedup vs baseline: 1.0222x; 1.0222x over previous
//
#include <hip/hip_runtime.h>
#include <hip/hip_bf16.h>

// Problem constants
#define D_DIM   25088
#define B_ROWS  2048
#define C_CLS   100
#define NT      7            // 7 tiles of 16 cols -> 112 padded classes
#define NPAD    112
#define KSTEPS_TOTAL 784     // 25088 / 32
#define OUTER   14           // outer K-splits (grid.y)
#define INNER   4            // inner K-split across the 4 waves of a block
#define KW      14           // K-steps per wave: 784 / (14*4)
#define PREP_G  4
#define EPS     1e-8f
#define LROW    113          // padded LDS row stride (floats)
#define LWAVE   (16*LROW)    // per-wave LDS slab (floats)

typedef __bf16 bf16x8 __attribute__((ext_vector_type(8)));
typedef float  f32x4  __attribute__((ext_vector_type(4)));

// RNE float->bf16, pack two into one dword
__device__ __forceinline__ unsigned bfpack2(float lo, float hi) {
    unsigned a = __builtin_bit_cast(unsigned, lo);
    unsigned b = __builtin_bit_cast(unsigned, hi);
    a += 0x7FFFu + ((a >> 16) & 1u);
    b += 0x7FFFu + ((b >> 16) & 1u);
    return (a >> 16) | (b & 0xFFFF0000u);
}

// ---------------- prep: pack weight into MFMA B-fragment order + partial sumsq ----
__global__ __launch_bounds__(448) void prep_kernel(const float* __restrict__ w,
                                                   float* __restrict__ wnorm2,
                                                   uint4* __restrict__ wpack) {
    int tid  = threadIdx.x;
    int t    = tid >> 6;
    int quad = (tid >> 4) & 3;
    int n    = tid & 15;
    int c    = t * 16 + n;
    bool real = (c < C_CLS);
    const float* row = w + (size_t)c * D_DIM + quad * 8;
    float s = 0.f;
#pragma unroll
    for (int g = 0; g < PREP_G; ++g) {
        int gstep = blockIdx.x * PREP_G + g;
        f32x4 v0 = {0.f,0.f,0.f,0.f}, v1 = {0.f,0.f,0.f,0.f};
        if (real) {
            v0 = *(const f32x4*)(row + gstep * 32);
            v1 = *(const f32x4*)(row + gstep * 32 + 4);
        }
        s += v0[0]*v0[0] + v0[1]*v0[1] + v0[2]*v0[2] + v0[3]*v0[3]
           + v1[0]*v1[0] + v1[1]*v1[1] + v1[2]*v1[2] + v1[3]*v1[3];
        uint4 o;
        o.x = bfpack2(v0[0], v0[1]);
        o.y = bfpack2(v0[2], v0[3]);
        o.z = bfpack2(v1[0], v1[1]);
        o.w = bfpack2(v1[2], v1[3]);
        wpack[(size_t)gstep * 448 + tid] = o;
    }
    s += __shfl_xor(s, 16, 64);
    s += __shfl_xor(s, 32, 64);
    if (quad == 0 && real) atomicAdd(&wnorm2[c], s);
}

// ---------------- main GEMM ----------------
// Block = 4 waves, one 16-row M-tile, all 112 cols. K split OUTER(grid.y) x INNER(wave).
// Cross-wave K-reduction via LDS; ONE plain coalesced store per block into slab[outer].
__global__ __launch_bounds__(256) void gemm_kernel(const float* __restrict__ feat,
                                                   const uint4* __restrict__ wpack,
                                                   float* __restrict__ slab,
                                                   float* __restrict__ fnorm2) {
    __shared__ float lred[4 * LWAVE];
    __shared__ float lsq[64];
    int tid  = threadIdx.x;
    int wave = tid >> 6, lane = tid & 63;
    int m = lane & 15, quad = lane >> 4;
    int mt    = blockIdx.x;        // 0..127 M-tile
    int outer = blockIdx.y;        // 0..13
    int row = mt * 16 + m;
    int gstep0 = (outer * INNER + wave) * KW;

    const float* pA = feat + (size_t)row * D_DIM + gstep0 * 32 + quad * 8;
    const uint4* pB = wpack + (size_t)gstep0 * 448 + lane;

    f32x4 acc[NT];
#pragma unroll
    for (int t = 0; t < NT; ++t) acc[t] = (f32x4){0.f,0.f,0.f,0.f};
    float sumsq = 0.f;

    // depth-2 software pipeline on A
    f32x4 c0 = *(const f32x4*)(pA);
    f32x4 c1 = *(const f32x4*)(pA + 4);
    f32x4 n0 = *(const f32x4*)(pA + 32);
    f32x4 n1 = *(const f32x4*)(pA + 36);

#pragma unroll 2
    for (int s = 0; s < KW; ++s) {
        f32x4 f0 = c0, f1 = c1;
        if (s + 2 < KW) {
            f0 = *(const f32x4*)(pA + (s + 2) * 32);
            f1 = *(const f32x4*)(pA + (s + 2) * 32 + 4);
        }
        sumsq += c0[0]*c0[0] + c0[1]*c0[1] + c0[2]*c0[2] + c0[3]*c0[3]
               + c1[0]*c1[0] + c1[1]*c1[1] + c1[2]*c1[2] + c1[3]*c1[3];
        uint4 ap;
        ap.x = bfpack2(c0[0], c0[1]);
        ap.y = bfpack2(c0[2], c0[3]);
        ap.z = bfpack2(c1[0], c1[1]);
        ap.w = bfpack2(c1[2], c1[3]);
        bf16x8 afrag = __builtin_bit_cast(bf16x8, ap);
#pragma unroll
        for (int t = 0; t < NT; ++t) {
            bf16x8 bfrag = __builtin_bit_cast(bf16x8, pB[s * 448 + t * 64]);
            acc[t] = __builtin_amdgcn_mfma_f32_16x16x32_bf16(afrag, bfrag, acc[t], 0, 0, 0);
        }
        c0 = n0; c1 = n1; n0 = f0; n1 = f1;
    }

    // per-wave sumsq for row m (reduce over quads), park in LDS
    sumsq += __shfl_xor(sumsq, 16, 64);
    sumsq += __shfl_xor(sumsq, 32, 64);
    if (quad == 0) lsq[wave * 16 + m] = sumsq;

    // park accumulators: C/D layout col = t*16+m, row = quad*4+r
#pragma unroll
    for (int t = 0; t < NT; ++t)
#pragma unroll
        for (int r = 0; r < 4; ++r)
            lred[wave * LWAVE + (quad * 4 + r) * LROW + t * 16 + m] = acc[t][r];

    __syncthreads();

    // block-level reduce over the 4 waves + single coalesced store
#pragma unroll
    for (int i = 0; i < 7; ++i) {
        int e = tid + i * 256;             // 0..1791
        int r = e / NPAD, c = e - r * NPAD;
        int li = r * LROW + c;
        float v = lred[li] + lred[LWAVE + li] + lred[2 * LWAVE + li] + lred[3 * LWAVE + li];
        slab[((size_t)outer * B_ROWS + mt * 16 + r) * NPAD + c] = v;
    }
    if (tid < 16)
        atomicAdd(&fnorm2[mt * 16 + tid],
                  lsq[tid] + lsq[16 + tid] + lsq[32 + tid] + lsq[48 + tid]);
}

// ---------------- per-row log-softmax / NLL / argmax: one wave per row ----------------
__global__ __launch_bounds__(256) void finalize_kernel(const float* __restrict__ slab,
                                                       const float* __restrict__ fnorm2,
                                                       const float* __restrict__ wnorm2,
                                                       const int* __restrict__ label,
                                                       float* __restrict__ scal) {
    int row = (blockIdx.x * 256 + threadIdx.x) >> 6;
    int lane = threadIdx.x & 63;
    if (row >= B_ROWS) return;
    float finv = 10.0f / fmaxf(sqrtf(fnorm2[row]), EPS);

    int c0 = lane, c1 = lane + 64;
    float a0 = 0.f, a1 = 0.f;
#pragma unroll
    for (int o = 0; o < OUTER; ++o) {
        const float* pr = slab + ((size_t)o * B_ROWS + row) * NPAD;
        a0 += pr[c0];
        if (c1 < C_CLS) a1 += pr[c1];
    }
    float l0 = (c0 < C_CLS) ? a0 * (finv / fmaxf(sqrtf(wnorm2[c0]), EPS)) : -1e30f;
    float l1 = (c1 < C_CLS) ? a1 * (finv / fmaxf(sqrtf(wnorm2[c1]), EPS)) : -1e30f;

    // argmax (keep smaller index on ties)
    float mx = l0; int am = c0;
    if (l1 > mx) { mx = l1; am = c1; }
    for (int o = 1; o < 64; o <<= 1) {
        float om = __shfl_xor(mx, o, 64);
        int   oa = __shfl_xor(am, o, 64);
        if (om > mx || (om == mx && oa < am)) { mx = om; am = oa; }
    }
    float se = expf(l0 - mx) + expf(l1 - mx);
    for (int o = 1; o < 64; o <<= 1) se += __shfl_xor(se, o, 64);

    int lab = label[row];
    int labc = (lab < 0) ? 0 : lab;
    float lv = (labc >= 64) ? l1 : l0;
    float ll = __shfl(lv, labc & 63, 64);

    if (lane == 0 && lab >= 0) {
        float lse = mx + logf(se);
        atomicAdd(&scal[0], lse - ll);
        atomicAdd(&scal[1], (am == lab) ? 1.f : 0.f);
        atomicAdd(&scal[2], 1.f);
    }
}

__global__ void out_kernel(const float* __restrict__ scal, float* __restrict__ out) {
    out[0] = scal[0] / fmaxf(scal[2], 1.0f);
    out[1] = scal[1] / (scal[2] + 1e-10f);
}

// Workspace layout (bytes):
//   [0, 12845056)            slab: 14 x 2048 x 112 f32 (written once, no zeroing)
//   [12845056, 12853248)     fnorm2: 2048 f32 (zeroed)
//   [12853248, 12853264)     scalars: 4 f32 (zeroed)
//   [12853264, 12853712)     wnorm2: 112 f32 (zeroed)
//   [12853760, 18473472)     wpack: 784*448 uint4 bf16 B-fragments
extern "C" void kernel_launch(void* const* d_in, const int* in_sizes, int n_in,
                              void* d_out, int out_size, void* d_ws, size_t ws_size,
                              hipStream_t stream) {
    const float* feat   = (const float*)d_in[0];
    const int*   label  = (const int*)d_in[1];
    const float* weight = (const float*)d_in[2];
    float* out = (float*)d_out;

    char* ws = (char*)d_ws;
    float* slab   = (float*)(ws);
    float* fnorm2 = (float*)(ws + 12845056);
    float* scal   = (float*)(ws + 12853248);
    float* wnorm2 = (float*)(ws + 12853264);
    uint4* wpack  = (uint4*)(ws + 12853760);

    hipMemsetAsync(ws + 12845056, 0, 8704, stream);
    prep_kernel<<<KSTEPS_TOTAL / PREP_G, 448, 0, stream>>>(weight, wnorm2, wpack);
    gemm_kernel<<<dim3(B_ROWS / 16, OUTER), 256, 0, stream>>>(feat, wpack, slab, fnorm2);
    finalize_kernel<<<B_ROWS / 4, 256, 0, stream>>>(slab, fnorm2, wnorm2, label, scal);
    out_kernel<<<1, 1, 0, stream>>>(scal, out);
}